// Round 3
// baseline (288.023 us; speedup 1.0000x reference)
//
#include <hip/hip_runtime.h>
#include <hip/hip_bf16.h>

#define VOCAB 50257
#define EMBED 128
#define NSENT 50
#define TC 20
#define TQ 20
#define BATCH 64
#define NHOPS 3
#define GRID 512
#define VT 64
#define NTILE ((VOCAB + VT - 1) / VT)   // 786
#define NUNIT (BATCH * NSENT + BATCH)   // 3264

typedef __bf16 bf16x8 __attribute__((ext_vector_type(8)));
typedef float  f32x4v __attribute__((ext_vector_type(4)));

struct WTile { bf16x8 wb[4]; float bl; };

// B-operand fragment for out-tile `tile`: 16 v's per wave, 8 bf16 per kc.
__device__ __forceinline__ WTile load_wtile(
    const float* __restrict__ W_lin, const float* __restrict__ b_lin,
    int tile, int wave, int m, int quad)
{
    WTile wt;
    const int v  = tile * VT + wave * 16 + m;
    const int vc = (v < VOCAB) ? v : (VOCAB - 1);
    const float* wrow = W_lin + (long)vc * EMBED;
    #pragma unroll
    for (int kc = 0; kc < 4; kc++) {
        const int k0 = kc * 32 + quad * 8;
        f32x4v w0 = *(const f32x4v*)(wrow + k0);
        f32x4v w1 = *(const f32x4v*)(wrow + k0 + 4);
        wt.wb[kc][0] = (__bf16)w0[0]; wt.wb[kc][1] = (__bf16)w0[1];
        wt.wb[kc][2] = (__bf16)w0[2]; wt.wb[kc][3] = (__bf16)w0[3];
        wt.wb[kc][4] = (__bf16)w1[0]; wt.wb[kc][5] = (__bf16)w1[1];
        wt.wb[kc][6] = (__bf16)w1[2]; wt.wb[kc][7] = (__bf16)w1[3];
    }
    wt.bl = b_lin[vc];
    return wt;
}

__global__ void __launch_bounds__(256) k_fused(
    const int* __restrict__ stories, const int* __restrict__ masks,
    const int* __restrict__ questions,
    const float* __restrict__ W_A, const float* __restrict__ W_B,
    const float* __restrict__ W_C,
    const float* __restrict__ W_AT, const float* __restrict__ W_CT,
    const float* __restrict__ W_lin, const float* __restrict__ b_lin,
    float* __restrict__ out, float* __restrict__ ws,
    unsigned* __restrict__ cnt)   // cnt[0]=embDone, cnt[1]=uDone (pre-zeroed)
{
    // 53248 B, aliased: phaseA sred[8][128]; phaseB smc|su|sp|ssc|spo
    __shared__ __align__(16) float lds[13312];

    float*  ws_m   = ws;
    float*  ws_c   = ws + BATCH * NSENT * EMBED;
    float*  ws_u   = ws + 2 * BATCH * NSENT * EMBED;
    __bf16* ws_ubf = (__bf16*)(ws_u + BATCH * EMBED);

    const int tid  = threadIdx.x;
    const int g    = blockIdx.x;
    const int wave = tid >> 6, lane = tid & 63;
    const int m    = lane & 15, quad = lane >> 4;

    // ---------------- Phase A: embedding sums (grid-stride, all blocks) ----------------
    {
        float (*sred)[128] = (float (*)[128])lds;
        const int grp = tid >> 5, gl = tid & 31;
        for (int unit = g; unit < NUNIT; unit += GRID) {
            if (unit < BATCH * NSENT) {
                const int b = unit / NSENT, i = unit % NSENT;
                const int* mrow = masks + (b * NSENT + i) * TC;
                int c0 = 0;
                #pragma unroll
                for (int t = 0; t < TC; t++) c0 += (mrow[t] == 0);
                const int te = (c0 >= 1) ? (i + 1) : 0;

                const int* srow = stories + (b * NSENT + i) * TC;
                const int table = grp >> 2, sub = grp & 3;
                const float* T = table ? W_C : W_A;
                f32x4v acc = {0.f, 0.f, 0.f, 0.f};
                #pragma unroll
                for (int t = 0; t < 5; t++) {
                    const int tok = srow[sub + t * 4];
                    acc += *(const f32x4v*)(T + (long)tok * EMBED + gl * 4);
                }
                *(f32x4v*)&sred[grp][gl * 4] = acc;
                __syncthreads();
                const int tb = tid >> 7, d = tid & 127;
                const float* TT = tb ? W_CT : W_AT;
                float v = sred[tb * 4 + 0][d] + sred[tb * 4 + 1][d]
                        + sred[tb * 4 + 2][d] + sred[tb * 4 + 3][d]
                        + TT[te * EMBED + d];
                (tb ? ws_c : ws_m)[(b * NSENT + i) * EMBED + d] = v;
                __syncthreads();
            } else {
                const int b = unit - BATCH * NSENT;
                f32x4v acc = {0.f, 0.f, 0.f, 0.f};
                for (int t = grp; t < TQ; t += 8) {
                    const int tok = questions[b * TQ + t];
                    acc += *(const f32x4v*)(W_B + (long)tok * EMBED + gl * 4);
                }
                *(f32x4v*)&sred[grp][gl * 4] = acc;
                __syncthreads();
                if (tid < EMBED) {
                    float v = 0.f;
                    #pragma unroll
                    for (int gg = 0; gg < 8; gg++) v += sred[gg][tid];
                    ws_u[b * EMBED + tid] = v;
                }
                __syncthreads();
            }
        }
    }
    // publish phase-A results (device-scope release)
    __threadfence();
    if (tid == 0) atomicAdd(&cnt[0], 1u);

    // W_lin out-tile prefetch for this block's tiles (latency hides under hops)
    WTile w0 = load_wtile(W_lin, b_lin, g, wave, m, quad);
    const int t1 = g + GRID;
    const bool has1 = (t1 < NTILE);
    WTile w1 = {};
    if (has1) w1 = load_wtile(W_lin, b_lin, t1, wave, m, quad);

    // ---------------- Phase B: hops on blocks 0..63 ----------------
    if (g < BATCH) {
        if (tid == 0) {
            while (__hip_atomic_load(&cnt[0], __ATOMIC_RELAXED,
                                     __HIP_MEMORY_SCOPE_AGENT) < GRID)
                __builtin_amdgcn_s_sleep(1);
        }
        __syncthreads();
        __threadfence();   // acquire: invalidate stale cached ws_m/ws_c

        float* smc = lds;                 // m: [0..6399], c: [6400..12799]
        float* su  = lds + 12800;
        float* sp  = lds + 12928;
        float* ssc = lds + 12992;
        float (*spo)[EMBED] = (float (*)[EMBED])(lds + 13056);

        const f32x4v* gm = (const f32x4v*)(ws_m + g * NSENT * EMBED);
        const f32x4v* gc = (const f32x4v*)(ws_c + g * NSENT * EMBED);
        f32x4v* s4 = (f32x4v*)smc;
        for (int idx = tid; idx < NSENT * EMBED / 4; idx += 256) {
            s4[idx] = gm[idx];
            s4[NSENT * EMBED / 4 + idx] = gc[idx];
        }
        if (tid < EMBED) su[tid] = ws_u[g * EMBED + tid];
        __syncthreads();

        const int d128 = tid & 127, hf = tid >> 7;
        for (int hop = 0; hop < NHOPS; hop++) {
            for (int i = wave; i < NSENT; i += 4) {
                float s = smc[i * EMBED + lane] * su[lane]
                        + smc[i * EMBED + 64 + lane] * su[64 + lane];
                #pragma unroll
                for (int off = 32; off >= 1; off >>= 1) s += __shfl_xor(s, off);
                if (lane == 0) ssc[i] = s;
            }
            __syncthreads();
            if (tid < 64) {
                float v = (tid < NSENT) ? ssc[tid] : -1e30f;
                float mx = v;
                #pragma unroll
                for (int off = 32; off >= 1; off >>= 1) mx = fmaxf(mx, __shfl_xor(mx, off));
                float e = (tid < NSENT) ? expf(v - mx) : 0.f;
                float sum = e;
                #pragma unroll
                for (int off = 32; off >= 1; off >>= 1) sum += __shfl_xor(sum, off);
                sp[tid] = e / sum;
            }
            __syncthreads();
            {
                float o = 0.f;
                #pragma unroll
                for (int k = 0; k < 25; k++) {
                    const int i = hf * 25 + k;
                    o += smc[NSENT * EMBED + i * EMBED + d128] * sp[i];
                }
                spo[hf][d128] = o;
            }
            __syncthreads();
            if (tid < EMBED) su[tid] += spo[0][tid] + spo[1][tid];
            __syncthreads();
        }
        if (tid < EMBED) ws_ubf[g * EMBED + tid] = (__bf16)su[tid];
        __syncthreads();
        __threadfence();   // release u_bf
        if (tid == 0) atomicAdd(&cnt[1], 1u);
    }

    // ---------------- Phase C: wait for u, then out tiles ----------------
    if (tid == 0) {
        while (__hip_atomic_load(&cnt[1], __ATOMIC_RELAXED,
                                 __HIP_MEMORY_SCOPE_AGENT) < BATCH)
            __builtin_amdgcn_s_sleep(1);
    }
    __syncthreads();
    __threadfence();       // acquire: u_bf

    bf16x8 ab[4][4];   // [kc][bt], static indexing only
    #pragma unroll
    for (int kc = 0; kc < 4; kc++) {
        const int k0 = kc * 32 + quad * 8;
        #pragma unroll
        for (int bt = 0; bt < 4; bt++)
            ab[kc][bt] = *(const bf16x8*)(ws_ubf + (bt * 16 + m) * EMBED + k0);
    }
    {
        f32x4v acc[4] = {};
        #pragma unroll
        for (int kc = 0; kc < 4; kc++)
            #pragma unroll
            for (int bt = 0; bt < 4; bt++)
                acc[bt] = __builtin_amdgcn_mfma_f32_16x16x32_bf16(ab[kc][bt], w0.wb[kc], acc[bt], 0, 0, 0);
        const int v = g * VT + wave * 16 + m;
        if (v < VOCAB) {
            #pragma unroll
            for (int bt = 0; bt < 4; bt++)
                #pragma unroll
                for (int r = 0; r < 4; r++)
                    out[(long)(bt * 16 + quad * 4 + r) * VOCAB + v] = acc[bt][r] + w0.bl;
        }
    }
    if (has1) {
        f32x4v acc[4] = {};
        #pragma unroll
        for (int kc = 0; kc < 4; kc++)
            #pragma unroll
            for (int bt = 0; bt < 4; bt++)
                acc[bt] = __builtin_amdgcn_mfma_f32_16x16x32_bf16(ab[kc][bt], w1.wb[kc], acc[bt], 0, 0, 0);
        const int v = t1 * VT + wave * 16 + m;
        if (v < VOCAB) {
            #pragma unroll
            for (int bt = 0; bt < 4; bt++)
                #pragma unroll
                for (int r = 0; r < 4; r++)
                    out[(long)(bt * 16 + quad * 4 + r) * VOCAB + v] = acc[bt][r] + w1.bl;
        }
    }
}

extern "C" void kernel_launch(void* const* d_in, const int* in_sizes, int n_in,
                              void* d_out, int out_size, void* d_ws, size_t ws_size,
                              hipStream_t stream) {
    const int*   stories   = (const int*)d_in[0];
    const int*   questions = (const int*)d_in[1];
    const int*   masks     = (const int*)d_in[2];
    const float* W_A       = (const float*)d_in[3];
    const float* W_B       = (const float*)d_in[4];
    const float* W_C       = (const float*)d_in[5];
    const float* W_AT      = (const float*)d_in[6];
    const float* W_CT      = (const float*)d_in[7];
    const float* W_lin     = (const float*)d_in[8];
    const float* b_lin     = (const float*)d_in[9];
    float* out = (float*)d_out;
    float* ws  = (float*)d_ws;
    unsigned* cnt = (unsigned*)((char*)d_ws + (32u << 20));  // far past data region

    hipMemsetAsync(cnt, 0, 2 * sizeof(unsigned), stream);
    k_fused<<<dim3(GRID), dim3(256), 0, stream>>>(
        stories, masks, questions, W_A, W_B, W_C, W_AT, W_CT,
        W_lin, b_lin, out, ws, cnt);
}

// Round 4
// 215.389 us; speedup vs baseline: 1.3372x; 1.3372x over previous
//
#include <hip/hip_runtime.h>
#include <hip/hip_bf16.h>

#define VOCAB 50257
#define EMBED 128
#define NSENT 50
#define TC 20
#define TQ 20
#define BATCH 64
#define NHOPS 3
#define VT 64
#define NTILE ((VOCAB + VT - 1) / VT)   // 786
#define GRID2 768                        // = 3 blocks/CU * 256 CU, all resident

typedef __bf16 bf16x8 __attribute__((ext_vector_type(8)));
typedef float  f32x4v __attribute__((ext_vector_type(4)));

// ---------------------------------------------------------------------------
// K1: embedding sums (verified round-1 code). 3264 blocks, 4KB LDS -> high
// occupancy for the latency-bound random-row gathers.
// ---------------------------------------------------------------------------
__global__ void __launch_bounds__(256) k_embed(
    const int* __restrict__ stories, const int* __restrict__ masks,
    const int* __restrict__ questions,
    const float* __restrict__ W_A, const float* __restrict__ W_B,
    const float* __restrict__ W_C,
    const float* __restrict__ W_AT, const float* __restrict__ W_CT,
    float* __restrict__ ws_m, float* __restrict__ ws_c, float* __restrict__ ws_u)
{
    __shared__ float sred[8][128];
    const int blk = blockIdx.x;
    const int tid = threadIdx.x;
    const int grp = tid >> 5;
    const int gl  = tid & 31;

    if (blk < BATCH * NSENT) {
        const int b = blk / NSENT;
        const int i = blk % NSENT;
        const int* mrow = masks + (b * NSENT + i) * TC;
        int cnt = 0;
        #pragma unroll
        for (int t = 0; t < TC; t++) cnt += (mrow[t] == 0);
        const int te = (cnt >= 1) ? (i + 1) : 0;

        const int* srow = stories + (b * NSENT + i) * TC;
        const int table = grp >> 2;
        const int sub   = grp & 3;
        const float* T = table ? W_C : W_A;

        f32x4v acc = {0.f, 0.f, 0.f, 0.f};
        #pragma unroll
        for (int t = 0; t < 5; t++) {
            const int tok = srow[sub + t * 4];
            acc += *(const f32x4v*)(T + (long)tok * EMBED + gl * 4);
        }
        *(f32x4v*)&sred[grp][gl * 4] = acc;
        __syncthreads();

        const int tb = tid >> 7, d = tid & 127;
        const float* TT = tb ? W_CT : W_AT;
        float v = sred[tb * 4 + 0][d] + sred[tb * 4 + 1][d]
                + sred[tb * 4 + 2][d] + sred[tb * 4 + 3][d]
                + TT[te * EMBED + d];
        float* dst = tb ? ws_c : ws_m;
        dst[(b * NSENT + i) * EMBED + d] = v;
    } else {
        const int b = blk - BATCH * NSENT;
        f32x4v acc = {0.f, 0.f, 0.f, 0.f};
        for (int t = grp; t < TQ; t += 8) {
            const int tok = questions[b * TQ + t];
            acc += *(const f32x4v*)(W_B + (long)tok * EMBED + gl * 4);
        }
        *(f32x4v*)&sred[grp][gl * 4] = acc;
        __syncthreads();
        if (tid < EMBED) {
            float v = 0.f;
            #pragma unroll
            for (int g = 0; g < 8; g++) v += sred[g][tid];
            ws_u[b * EMBED + tid] = v;
        }
    }
}

struct WTile { bf16x8 wb[4]; float bl; };

__device__ __forceinline__ WTile load_wtile(
    const float* __restrict__ W_lin, const float* __restrict__ b_lin,
    int tile, int wave, int m, int quad)
{
    WTile wt;
    const int v  = tile * VT + wave * 16 + m;
    const int vc = (v < VOCAB) ? v : (VOCAB - 1);
    const float* wrow = W_lin + (long)vc * EMBED;
    #pragma unroll
    for (int kc = 0; kc < 4; kc++) {
        const int k0 = kc * 32 + quad * 8;
        f32x4v w0 = *(const f32x4v*)(wrow + k0);
        f32x4v w1 = *(const f32x4v*)(wrow + k0 + 4);
        wt.wb[kc][0] = (__bf16)w0[0]; wt.wb[kc][1] = (__bf16)w0[1];
        wt.wb[kc][2] = (__bf16)w0[2]; wt.wb[kc][3] = (__bf16)w0[3];
        wt.wb[kc][4] = (__bf16)w1[0]; wt.wb[kc][5] = (__bf16)w1[1];
        wt.wb[kc][6] = (__bf16)w1[2]; wt.wb[kc][7] = (__bf16)w1[3];
    }
    wt.bl = b_lin[vc];
    return wt;
}

// ---------------------------------------------------------------------------
// K2: hops (blocks 0..63) + output GEMM (all 768 blocks), fused so the 25.7MB
// W_lin read (register-prefetched first) overlaps the hops. m/c visibility is
// guaranteed by the kernel boundary; the only sync is one counter for u.
// ---------------------------------------------------------------------------
__global__ void __launch_bounds__(256, 3) k_hops_out(
    const float* __restrict__ ws_m, const float* __restrict__ ws_c,
    const float* __restrict__ ws_u, __bf16* __restrict__ ws_ubf,
    const float* __restrict__ W_lin, const float* __restrict__ b_lin,
    float* __restrict__ out, unsigned* __restrict__ cnt)
{
    __shared__ __align__(16) float lds[13312];   // 53248 B -> 3 blocks/CU

    const int tid  = threadIdx.x;
    const int g    = blockIdx.x;
    const int wave = tid >> 6, lane = tid & 63;
    const int m    = lane & 15, quad = lane >> 4;

    // W_lin out-tile register prefetch: issued first, completes under hops.
    WTile w0 = load_wtile(W_lin, b_lin, g, wave, m, quad);
    const bool has1 = (g >= GRID2 - (NTILE - GRID2));          // blocks 750..767
    WTile w1 = {};
    if (has1) w1 = load_wtile(W_lin, b_lin, g + (NTILE - GRID2), wave, m, quad);

    if (g < BATCH) {
        float* smc = lds;                 // m: [0..6399], c: [6400..12799]
        float* su  = lds + 12800;
        float* sp  = lds + 12928;
        float* ssc = lds + 12992;
        float (*spo)[EMBED] = (float (*)[EMBED])(lds + 13056);

        const f32x4v* gm = (const f32x4v*)(ws_m + g * NSENT * EMBED);
        const f32x4v* gc = (const f32x4v*)(ws_c + g * NSENT * EMBED);
        f32x4v* s4 = (f32x4v*)smc;
        for (int idx = tid; idx < NSENT * EMBED / 4; idx += 256) {
            s4[idx] = gm[idx];
            s4[NSENT * EMBED / 4 + idx] = gc[idx];
        }
        if (tid < EMBED) su[tid] = ws_u[g * EMBED + tid];
        __syncthreads();

        const int d128 = tid & 127, hf = tid >> 7;
        for (int hop = 0; hop < NHOPS; hop++) {
            for (int i = wave; i < NSENT; i += 4) {
                float s = smc[i * EMBED + lane] * su[lane]
                        + smc[i * EMBED + 64 + lane] * su[64 + lane];
                #pragma unroll
                for (int off = 32; off >= 1; off >>= 1) s += __shfl_xor(s, off);
                if (lane == 0) ssc[i] = s;
            }
            __syncthreads();
            if (tid < 64) {
                float v = (tid < NSENT) ? ssc[tid] : -1e30f;
                float mx = v;
                #pragma unroll
                for (int off = 32; off >= 1; off >>= 1) mx = fmaxf(mx, __shfl_xor(mx, off));
                float e = (tid < NSENT) ? expf(v - mx) : 0.f;
                float sum = e;
                #pragma unroll
                for (int off = 32; off >= 1; off >>= 1) sum += __shfl_xor(sum, off);
                sp[tid] = e / sum;
            }
            __syncthreads();
            {
                float o = 0.f;
                #pragma unroll
                for (int k = 0; k < 25; k++) {
                    const int i = hf * 25 + k;
                    o += smc[NSENT * EMBED + i * EMBED + d128] * sp[i];
                }
                spo[hf][d128] = o;
            }
            __syncthreads();
            if (tid < EMBED) su[tid] += spo[0][tid] + spo[1][tid];
            __syncthreads();
        }
        if (tid < EMBED) ws_ubf[g * EMBED + tid] = (__bf16)su[tid];
        __syncthreads();
        __threadfence();                      // release u_bf (all threads fence own writes)
        if (tid == 0) atomicAdd(cnt, 1u);
    }

    // wait for all 64 u-rows; coarse poll (s_sleep(32) ~ 2k cycles) to keep
    // fabric traffic from 704 spinners negligible.
    if (tid == 0) {
        while (__hip_atomic_load(cnt, __ATOMIC_RELAXED,
                                 __HIP_MEMORY_SCOPE_AGENT) < BATCH)
            __builtin_amdgcn_s_sleep(32);
    }
    __syncthreads();
    __threadfence();                          // acquire u_bf

    bf16x8 ab[4][4];   // [kc][bt], static indexing only
    #pragma unroll
    for (int kc = 0; kc < 4; kc++) {
        const int k0 = kc * 32 + quad * 8;
        #pragma unroll
        for (int bt = 0; bt < 4; bt++)
            ab[kc][bt] = *(const bf16x8*)(ws_ubf + (bt * 16 + m) * EMBED + k0);
    }
    {
        f32x4v acc[4] = {};
        #pragma unroll
        for (int kc = 0; kc < 4; kc++)
            #pragma unroll
            for (int bt = 0; bt < 4; bt++)
                acc[bt] = __builtin_amdgcn_mfma_f32_16x16x32_bf16(ab[kc][bt], w0.wb[kc], acc[bt], 0, 0, 0);
        const int v = g * VT + wave * 16 + m;
        if (v < VOCAB) {
            #pragma unroll
            for (int bt = 0; bt < 4; bt++)
                #pragma unroll
                for (int r = 0; r < 4; r++)
                    out[(long)(bt * 16 + quad * 4 + r) * VOCAB + v] = acc[bt][r] + w0.bl;
        }
    }
    if (has1) {
        f32x4v acc[4] = {};
        #pragma unroll
        for (int kc = 0; kc < 4; kc++)
            #pragma unroll
            for (int bt = 0; bt < 4; bt++)
                acc[bt] = __builtin_amdgcn_mfma_f32_16x16x32_bf16(ab[kc][bt], w1.wb[kc], acc[bt], 0, 0, 0);
        const int v = (g + (NTILE - GRID2)) * VT + wave * 16 + m;
        if (v < VOCAB) {
            #pragma unroll
            for (int bt = 0; bt < 4; bt++)
                #pragma unroll
                for (int r = 0; r < 4; r++)
                    out[(long)(bt * 16 + quad * 4 + r) * VOCAB + v] = acc[bt][r] + w1.bl;
        }
    }
}

extern "C" void kernel_launch(void* const* d_in, const int* in_sizes, int n_in,
                              void* d_out, int out_size, void* d_ws, size_t ws_size,
                              hipStream_t stream) {
    const int*   stories   = (const int*)d_in[0];
    const int*   questions = (const int*)d_in[1];
    const int*   masks     = (const int*)d_in[2];
    const float* W_A       = (const float*)d_in[3];
    const float* W_B       = (const float*)d_in[4];
    const float* W_C       = (const float*)d_in[5];
    const float* W_AT      = (const float*)d_in[6];
    const float* W_CT      = (const float*)d_in[7];
    const float* W_lin     = (const float*)d_in[8];
    const float* b_lin     = (const float*)d_in[9];
    float* out = (float*)d_out;
    float* ws  = (float*)d_ws;

    float*  ws_m   = ws;
    float*  ws_c   = ws + BATCH * NSENT * EMBED;
    float*  ws_u   = ws + 2 * BATCH * NSENT * EMBED;
    __bf16* ws_ubf = (__bf16*)(ws_u + BATCH * EMBED);
    unsigned* cnt  = (unsigned*)((char*)d_ws + (32u << 20));   // far past data region

    hipMemsetAsync(cnt, 0, sizeof(unsigned), stream);
    k_embed<<<dim3(BATCH * NSENT + BATCH), dim3(256), 0, stream>>>(
        stories, masks, questions, W_A, W_B, W_C, W_AT, W_CT, ws_m, ws_c, ws_u);
    k_hops_out<<<dim3(GRID2), dim3(256), 0, stream>>>(
        ws_m, ws_c, ws_u, ws_ubf, W_lin, b_lin, out, cnt);
}

// Round 5
// 183.930 us; speedup vs baseline: 1.5659x; 1.1710x over previous
//
#include <hip/hip_runtime.h>
#include <hip/hip_bf16.h>

#define VOCAB 50257
#define EMBED 128
#define NSENT 50
#define TC 20
#define TQ 20
#define BATCH 64
#define NHOPS 3
#define VT 64
#define NTILE ((VOCAB + VT - 1) / VT)   // 786
#define GRID2 768                        // = 3 blocks/CU * 256 CU, all resident

typedef __bf16 bf16x8 __attribute__((ext_vector_type(8)));
typedef float  f32x4v __attribute__((ext_vector_type(4)));

// ---------------------------------------------------------------------------
// K1: embedding sums (verified). 3264 blocks, 4KB LDS -> high occupancy for
// the latency-bound random-row gathers.
// ---------------------------------------------------------------------------
__global__ void __launch_bounds__(256) k_embed(
    const int* __restrict__ stories, const int* __restrict__ masks,
    const int* __restrict__ questions,
    const float* __restrict__ W_A, const float* __restrict__ W_B,
    const float* __restrict__ W_C,
    const float* __restrict__ W_AT, const float* __restrict__ W_CT,
    float* __restrict__ ws_m, float* __restrict__ ws_c, float* __restrict__ ws_u)
{
    __shared__ float sred[8][128];
    const int blk = blockIdx.x;
    const int tid = threadIdx.x;
    const int grp = tid >> 5;
    const int gl  = tid & 31;

    if (blk < BATCH * NSENT) {
        const int b = blk / NSENT;
        const int i = blk % NSENT;
        const int* mrow = masks + (b * NSENT + i) * TC;
        int cnt = 0;
        #pragma unroll
        for (int t = 0; t < TC; t++) cnt += (mrow[t] == 0);
        const int te = (cnt >= 1) ? (i + 1) : 0;

        const int* srow = stories + (b * NSENT + i) * TC;
        const int table = grp >> 2;
        const int sub   = grp & 3;
        const float* T = table ? W_C : W_A;

        f32x4v acc = {0.f, 0.f, 0.f, 0.f};
        #pragma unroll
        for (int t = 0; t < 5; t++) {
            const int tok = srow[sub + t * 4];
            acc += *(const f32x4v*)(T + (long)tok * EMBED + gl * 4);
        }
        *(f32x4v*)&sred[grp][gl * 4] = acc;
        __syncthreads();

        const int tb = tid >> 7, d = tid & 127;
        const float* TT = tb ? W_CT : W_AT;
        float v = sred[tb * 4 + 0][d] + sred[tb * 4 + 1][d]
                + sred[tb * 4 + 2][d] + sred[tb * 4 + 3][d]
                + TT[te * EMBED + d];
        float* dst = tb ? ws_c : ws_m;
        dst[(b * NSENT + i) * EMBED + d] = v;
    } else {
        const int b = blk - BATCH * NSENT;
        f32x4v acc = {0.f, 0.f, 0.f, 0.f};
        for (int t = grp; t < TQ; t += 8) {
            const int tok = questions[b * TQ + t];
            acc += *(const f32x4v*)(W_B + (long)tok * EMBED + gl * 4);
        }
        *(f32x4v*)&sred[grp][gl * 4] = acc;
        __syncthreads();
        if (tid < EMBED) {
            float v = 0.f;
            #pragma unroll
            for (int g = 0; g < 8; g++) v += sred[g][tid];
            ws_u[b * EMBED + tid] = v;
        }
    }
}

struct WTile { bf16x8 wb[4]; float bl; };

__device__ __forceinline__ WTile load_wtile(
    const float* __restrict__ W_lin, const float* __restrict__ b_lin,
    int tile, int wave, int m, int quad)
{
    WTile wt;
    const int v  = tile * VT + wave * 16 + m;
    const int vc = (v < VOCAB) ? v : (VOCAB - 1);
    const float* wrow = W_lin + (long)vc * EMBED;
    #pragma unroll
    for (int kc = 0; kc < 4; kc++) {
        const int k0 = kc * 32 + quad * 8;
        f32x4v w0 = *(const f32x4v*)(wrow + k0);
        f32x4v w1 = *(const f32x4v*)(wrow + k0 + 4);
        wt.wb[kc][0] = (__bf16)w0[0]; wt.wb[kc][1] = (__bf16)w0[1];
        wt.wb[kc][2] = (__bf16)w0[2]; wt.wb[kc][3] = (__bf16)w0[3];
        wt.wb[kc][4] = (__bf16)w1[0]; wt.wb[kc][5] = (__bf16)w1[1];
        wt.wb[kc][6] = (__bf16)w1[2]; wt.wb[kc][7] = (__bf16)w1[3];
    }
    wt.bl = b_lin[vc];
    return wt;
}

// ---------------------------------------------------------------------------
// K2: hops (blocks 0..63) + output GEMM (all 768 blocks).
// v3 sync fixes vs round 4:
//   (A) poll with far-atomic RMW atomicAdd(cnt,0) -- always coherent at LLC,
//       immune to the stale-L2-line spin that caused eviction-driven wakeup.
//   (B) acquire/release __threadfence() once per BLOCK (tid 0), not per
//       thread, ordered by __syncthreads (which drains vmcnt before
//       s_barrier) -- kills the 196k-cache-op fence storm.
// ---------------------------------------------------------------------------
__global__ void __launch_bounds__(256, 3) k_hops_out(
    const float* __restrict__ ws_m, const float* __restrict__ ws_c,
    const float* __restrict__ ws_u, __bf16* __restrict__ ws_ubf,
    const float* __restrict__ W_lin, const float* __restrict__ b_lin,
    float* __restrict__ out, unsigned* __restrict__ cnt)
{
    __shared__ __align__(16) float lds[13312];   // 53248 B -> 3 blocks/CU

    const int tid  = threadIdx.x;
    const int g    = blockIdx.x;
    const int wave = tid >> 6, lane = tid & 63;
    const int m    = lane & 15, quad = lane >> 4;

    // W_lin out-tile register prefetch: issued first, completes under hops.
    WTile w0 = load_wtile(W_lin, b_lin, g, wave, m, quad);
    const bool has1 = (g >= GRID2 - (NTILE - GRID2));          // blocks 750..767
    WTile w1 = {};
    if (has1) w1 = load_wtile(W_lin, b_lin, g + (NTILE - GRID2), wave, m, quad);

    if (g < BATCH) {
        float* smc = lds;                 // m: [0..6399], c: [6400..12799]
        float* su  = lds + 12800;
        float* sp  = lds + 12928;
        float* ssc = lds + 12992;
        float (*spo)[EMBED] = (float (*)[EMBED])(lds + 13056);

        const f32x4v* gm = (const f32x4v*)(ws_m + g * NSENT * EMBED);
        const f32x4v* gc = (const f32x4v*)(ws_c + g * NSENT * EMBED);
        f32x4v* s4 = (f32x4v*)smc;
        for (int idx = tid; idx < NSENT * EMBED / 4; idx += 256) {
            s4[idx] = gm[idx];
            s4[NSENT * EMBED / 4 + idx] = gc[idx];
        }
        if (tid < EMBED) su[tid] = ws_u[g * EMBED + tid];
        __syncthreads();

        const int d128 = tid & 127, hf = tid >> 7;
        for (int hop = 0; hop < NHOPS; hop++) {
            for (int i = wave; i < NSENT; i += 4) {
                float s = smc[i * EMBED + lane] * su[lane]
                        + smc[i * EMBED + 64 + lane] * su[64 + lane];
                #pragma unroll
                for (int off = 32; off >= 1; off >>= 1) s += __shfl_xor(s, off);
                if (lane == 0) ssc[i] = s;
            }
            __syncthreads();
            if (tid < 64) {
                float v = (tid < NSENT) ? ssc[tid] : -1e30f;
                float mx = v;
                #pragma unroll
                for (int off = 32; off >= 1; off >>= 1) mx = fmaxf(mx, __shfl_xor(mx, off));
                float e = (tid < NSENT) ? expf(v - mx) : 0.f;
                float sum = e;
                #pragma unroll
                for (int off = 32; off >= 1; off >>= 1) sum += __shfl_xor(sum, off);
                sp[tid] = e / sum;
            }
            __syncthreads();
            {
                float o = 0.f;
                #pragma unroll
                for (int k = 0; k < 25; k++) {
                    const int i = hf * 25 + k;
                    o += smc[NSENT * EMBED + i * EMBED + d128] * sp[i];
                }
                spo[hf][d128] = o;
            }
            __syncthreads();
            if (tid < EMBED) su[tid] += spo[0][tid] + spo[1][tid];
            __syncthreads();
        }
        if (tid < EMBED) ws_ubf[g * EMBED + tid] = (__bf16)su[tid];
        // all ubf writes issued and drained (syncthreads waits vmcnt(0))
        __syncthreads();
        if (tid == 0) {
            __threadfence();              // release: one L2 writeback per block
            atomicAdd(cnt, 1u);           // far-atomic at coherence point
        }
    }

    // ---- wait for all 64 u-rows: far-atomic poll with backoff ----
    if (tid == 0) {
        if (atomicAdd(cnt, 0u) < BATCH) {
            int it = 0;
            for (;;) {
                if (it < 16) __builtin_amdgcn_s_sleep(8);    // ~0.35 us
                else         __builtin_amdgcn_s_sleep(64);   // ~2.7 us
                if (atomicAdd(cnt, 0u) >= BATCH) break;
                ++it;
            }
        }
        __threadfence();                  // acquire: one L2 inv per block
    }
    __syncthreads();                      // orders the inval before all loads

    bf16x8 ab[4][4];   // [kc][bt], static indexing only
    #pragma unroll
    for (int kc = 0; kc < 4; kc++) {
        const int k0 = kc * 32 + quad * 8;
        #pragma unroll
        for (int bt = 0; bt < 4; bt++)
            ab[kc][bt] = *(const bf16x8*)(ws_ubf + (bt * 16 + m) * EMBED + k0);
    }
    {
        f32x4v acc[4] = {};
        #pragma unroll
        for (int kc = 0; kc < 4; kc++)
            #pragma unroll
            for (int bt = 0; bt < 4; bt++)
                acc[bt] = __builtin_amdgcn_mfma_f32_16x16x32_bf16(ab[kc][bt], w0.wb[kc], acc[bt], 0, 0, 0);
        const int v = g * VT + wave * 16 + m;
        if (v < VOCAB) {
            #pragma unroll
            for (int bt = 0; bt < 4; bt++)
                #pragma unroll
                for (int r = 0; r < 4; r++)
                    out[(long)(bt * 16 + quad * 4 + r) * VOCAB + v] = acc[bt][r] + w0.bl;
        }
    }
    if (has1) {
        f32x4v acc[4] = {};
        #pragma unroll
        for (int kc = 0; kc < 4; kc++)
            #pragma unroll
            for (int bt = 0; bt < 4; bt++)
                acc[bt] = __builtin_amdgcn_mfma_f32_16x16x32_bf16(ab[kc][bt], w1.wb[kc], acc[bt], 0, 0, 0);
        const int v = (g + (NTILE - GRID2)) * VT + wave * 16 + m;
        if (v < VOCAB) {
            #pragma unroll
            for (int bt = 0; bt < 4; bt++)
                #pragma unroll
                for (int r = 0; r < 4; r++)
                    out[(long)(bt * 16 + quad * 4 + r) * VOCAB + v] = acc[bt][r] + w1.bl;
        }
    }
}

extern "C" void kernel_launch(void* const* d_in, const int* in_sizes, int n_in,
                              void* d_out, int out_size, void* d_ws, size_t ws_size,
                              hipStream_t stream) {
    const int*   stories   = (const int*)d_in[0];
    const int*   questions = (const int*)d_in[1];
    const int*   masks     = (const int*)d_in[2];
    const float* W_A       = (const float*)d_in[3];
    const float* W_B       = (const float*)d_in[4];
    const float* W_C       = (const float*)d_in[5];
    const float* W_AT      = (const float*)d_in[6];
    const float* W_CT      = (const float*)d_in[7];
    const float* W_lin     = (const float*)d_in[8];
    const float* b_lin     = (const float*)d_in[9];
    float* out = (float*)d_out;
    float* ws  = (float*)d_ws;

    float*  ws_m   = ws;
    float*  ws_c   = ws + BATCH * NSENT * EMBED;
    float*  ws_u   = ws + 2 * BATCH * NSENT * EMBED;
    __bf16* ws_ubf = (__bf16*)(ws_u + BATCH * EMBED);
    unsigned* cnt  = (unsigned*)((char*)d_ws + (32u << 20));   // far past data region

    hipMemsetAsync(cnt, 0, sizeof(unsigned), stream);
    k_embed<<<dim3(BATCH * NSENT + BATCH), dim3(256), 0, stream>>>(
        stories, masks, questions, W_A, W_B, W_C, W_AT, W_CT, ws_m, ws_c, ws_u);
    k_hops_out<<<dim3(GRID2), dim3(256), 0, stream>>>(
        ws_m, ws_c, ws_u, ws_ubf, W_lin, b_lin, out, cnt);
}

// Round 6
// 164.018 us; speedup vs baseline: 1.7560x; 1.1214x over previous
//
#include <hip/hip_runtime.h>
#include <hip/hip_bf16.h>

#define VOCAB 50257
#define EMBED 128
#define NSENT 50
#define TC 20
#define TQ 20
#define BATCH 64
#define NHOPS 3

#define NWARM 786                       // W_lin L3-warm blocks (32KB each)
#define NMC   (BATCH * NSENT)           // 3200
#define W4TOT ((VOCAB * EMBED) / 4)     // 1,608,224 f32x4 in W_lin

typedef __bf16 bf16x8 __attribute__((ext_vector_type(8)));
typedef float  f32x4v __attribute__((ext_vector_type(4)));

// ---------------------------------------------------------------------------
// K1: embedding sums + W_lin L3 warm.
// Blocks [0,786): stream 32KB of W_lin each -> lands in die-level L3 while the
//   gather blocks are latency-stalled (gather phase runs ~2TB/s, BW to spare).
//   No sync needed: L3 is shared across XCDs; k_out reads it hot.
// Blocks [786,3986): m/c sentence gathers (verified round-1 code).
// Blocks [3986,4050): question embedding u.
// ---------------------------------------------------------------------------
__global__ void __launch_bounds__(256) k_embed(
    const int* __restrict__ stories, const int* __restrict__ masks,
    const int* __restrict__ questions,
    const float* __restrict__ W_A, const float* __restrict__ W_B,
    const float* __restrict__ W_C,
    const float* __restrict__ W_AT, const float* __restrict__ W_CT,
    const float* __restrict__ W_lin,
    float* __restrict__ ws_m, float* __restrict__ ws_c, float* __restrict__ ws_u)
{
    __shared__ float sred[8][128];
    const int blk = blockIdx.x;
    const int tid = threadIdx.x;
    const int grp = tid >> 5;
    const int gl  = tid & 31;

    if (blk < NWARM) {
        // warm 2048 f32x4 (32KB) of W_lin into L3; keep-alive via empty asm
        const long base4 = (long)blk * 2048;
        const f32x4v* w4 = (const f32x4v*)W_lin;
        f32x4v s = {0.f, 0.f, 0.f, 0.f};
        #pragma unroll
        for (int k = 0; k < 8; k++) {
            const long j = base4 + k * 256 + tid;
            if (j < W4TOT) s += w4[j];
        }
        float keep = s[0] + s[1] + s[2] + s[3];
        asm volatile("" :: "v"(keep));
        return;
    }

    if (blk < NWARM + NMC) {
        const int unit = blk - NWARM;
        const int b = unit / NSENT;
        const int i = unit % NSENT;
        const int* mrow = masks + (b * NSENT + i) * TC;
        int cnt = 0;
        #pragma unroll
        for (int t = 0; t < TC; t++) cnt += (mrow[t] == 0);
        const int te = (cnt >= 1) ? (i + 1) : 0;

        const int* srow = stories + (b * NSENT + i) * TC;
        const int table = grp >> 2;
        const int sub   = grp & 3;
        const float* T = table ? W_C : W_A;

        f32x4v acc = {0.f, 0.f, 0.f, 0.f};
        #pragma unroll
        for (int t = 0; t < 5; t++) {
            const int tok = srow[sub + t * 4];
            acc += *(const f32x4v*)(T + (long)tok * EMBED + gl * 4);
        }
        *(f32x4v*)&sred[grp][gl * 4] = acc;
        __syncthreads();

        const int tb = tid >> 7, d = tid & 127;
        const float* TT = tb ? W_CT : W_AT;
        float v = sred[tb * 4 + 0][d] + sred[tb * 4 + 1][d]
                + sred[tb * 4 + 2][d] + sred[tb * 4 + 3][d]
                + TT[te * EMBED + d];
        float* dst = tb ? ws_c : ws_m;
        dst[(b * NSENT + i) * EMBED + d] = v;
    } else {
        const int b = blk - (NWARM + NMC);
        f32x4v acc = {0.f, 0.f, 0.f, 0.f};
        for (int t = grp; t < TQ; t += 8) {
            const int tok = questions[b * TQ + t];
            acc += *(const f32x4v*)(W_B + (long)tok * EMBED + gl * 4);
        }
        *(f32x4v*)&sred[grp][gl * 4] = acc;
        __syncthreads();
        if (tid < EMBED) {
            float v = 0.f;
            #pragma unroll
            for (int g = 0; g < 8; g++) v += sred[g][tid];
            ws_u[b * EMBED + tid] = v;
        }
    }
}

// ---------------------------------------------------------------------------
// K2: 3 hops, one block per batch element, m/c staged in LDS (verified).
// ---------------------------------------------------------------------------
__global__ void __launch_bounds__(256) k_hops(
    const float* __restrict__ ws_m, const float* __restrict__ ws_c,
    const float* __restrict__ ws_u, __bf16* __restrict__ ws_ubf)
{
    __shared__ float smc[2 * NSENT * EMBED];
    __shared__ float su[EMBED];
    __shared__ float sp[64];
    __shared__ float ssc[64];
    __shared__ float spo[2][EMBED];

    const int b = blockIdx.x;
    const int tid = threadIdx.x;

    const f32x4v* gm = (const f32x4v*)(ws_m + b * NSENT * EMBED);
    const f32x4v* gc = (const f32x4v*)(ws_c + b * NSENT * EMBED);
    f32x4v* s4 = (f32x4v*)smc;
    for (int idx = tid; idx < NSENT * EMBED / 4; idx += 256) {
        s4[idx] = gm[idx];
        s4[NSENT * EMBED / 4 + idx] = gc[idx];
    }
    if (tid < EMBED) su[tid] = ws_u[b * EMBED + tid];
    __syncthreads();

    const int wave = tid >> 6, lane = tid & 63;
    const int d128 = tid & 127, hf = tid >> 7;
    for (int hop = 0; hop < NHOPS; hop++) {
        for (int i = wave; i < NSENT; i += 4) {
            float s = smc[i * EMBED + lane] * su[lane]
                    + smc[i * EMBED + 64 + lane] * su[64 + lane];
            #pragma unroll
            for (int off = 32; off >= 1; off >>= 1) s += __shfl_xor(s, off);
            if (lane == 0) ssc[i] = s;
        }
        __syncthreads();
        if (tid < 64) {
            float v = (tid < NSENT) ? ssc[tid] : -1e30f;
            float mx = v;
            #pragma unroll
            for (int off = 32; off >= 1; off >>= 1) mx = fmaxf(mx, __shfl_xor(mx, off));
            float e = (tid < NSENT) ? expf(v - mx) : 0.f;
            float sum = e;
            #pragma unroll
            for (int off = 32; off >= 1; off >>= 1) sum += __shfl_xor(sum, off);
            sp[tid] = e / sum;
        }
        __syncthreads();
        {
            float o = 0.f;
            #pragma unroll
            for (int k = 0; k < 25; k++) {
                const int i = hf * 25 + k;
                o += smc[NSENT * EMBED + i * EMBED + d128] * sp[i];
            }
            spo[hf][d128] = o;
        }
        __syncthreads();
        if (tid < EMBED) su[tid] += spo[0][tid] + spo[1][tid];
        __syncthreads();
    }
    if (tid < EMBED) ws_ubf[b * EMBED + tid] = (__bf16)su[tid];
}

// ---------------------------------------------------------------------------
// K3: out[b][v] = u[b].W_lin[v] + b_lin[v] via bf16 MFMA (verified round-1
// v2: 128-v tile, LDS transpose, nontemporal coalesced stores). W_lin is now
// L3-hot from k_embed's warm blocks.
// ---------------------------------------------------------------------------
#define VT 128
__global__ void __launch_bounds__(256) k_out(
    const __bf16* __restrict__ u_bf, const float* __restrict__ W_lin,
    const float* __restrict__ b_lin, float* __restrict__ out)
{
    __shared__ float sT[64][VT + 1];

    const int tid  = threadIdx.x;
    const int wave = tid >> 6, lane = tid & 63;
    const int m    = lane & 15;
    const int quad = lane >> 4;
    const int vbase = blockIdx.x * VT + wave * 32;

    f32x4v acc[2][4] = {};

    #pragma unroll
    for (int kc = 0; kc < 4; kc++) {
        const int k0 = kc * 32 + quad * 8;
        bf16x8 wb[2];
        #pragma unroll
        for (int s = 0; s < 2; s++) {
            int v = vbase + s * 16 + m;
            int vc = (v < VOCAB) ? v : (VOCAB - 1);
            const float* wrow = W_lin + (long)vc * EMBED;
            f32x4v w0 = *(const f32x4v*)(wrow + k0);
            f32x4v w1 = *(const f32x4v*)(wrow + k0 + 4);
            wb[s][0] = (__bf16)w0[0]; wb[s][1] = (__bf16)w0[1];
            wb[s][2] = (__bf16)w0[2]; wb[s][3] = (__bf16)w0[3];
            wb[s][4] = (__bf16)w1[0]; wb[s][5] = (__bf16)w1[1];
            wb[s][6] = (__bf16)w1[2]; wb[s][7] = (__bf16)w1[3];
        }
        #pragma unroll
        for (int bt = 0; bt < 4; bt++) {
            bf16x8 ab = *(const bf16x8*)(u_bf + (bt * 16 + m) * EMBED + k0);
            acc[0][bt] = __builtin_amdgcn_mfma_f32_16x16x32_bf16(ab, wb[0], acc[0][bt], 0, 0, 0);
            acc[1][bt] = __builtin_amdgcn_mfma_f32_16x16x32_bf16(ab, wb[1], acc[1][bt], 0, 0, 0);
        }
    }

    #pragma unroll
    for (int s = 0; s < 2; s++)
        #pragma unroll
        for (int bt = 0; bt < 4; bt++)
            #pragma unroll
            for (int r = 0; r < 4; r++)
                sT[bt * 16 + quad * 4 + r][wave * 32 + s * 16 + m] = acc[s][bt][r];
    __syncthreads();

    const int col = tid & 127;
    const int bh  = tid >> 7;
    const int v   = blockIdx.x * VT + col;
    if (v < VOCAB) {
        const float bl = b_lin[v];
        #pragma unroll
        for (int it = 0; it < 32; it++) {
            const int bb = bh * 32 + it;
            __builtin_nontemporal_store(sT[bb][col] + bl, &out[(long)bb * VOCAB + v]);
        }
    }
}

extern "C" void kernel_launch(void* const* d_in, const int* in_sizes, int n_in,
                              void* d_out, int out_size, void* d_ws, size_t ws_size,
                              hipStream_t stream) {
    const int*   stories   = (const int*)d_in[0];
    const int*   questions = (const int*)d_in[1];
    const int*   masks     = (const int*)d_in[2];
    const float* W_A       = (const float*)d_in[3];
    const float* W_B       = (const float*)d_in[4];
    const float* W_C       = (const float*)d_in[5];
    const float* W_AT      = (const float*)d_in[6];
    const float* W_CT      = (const float*)d_in[7];
    const float* W_lin     = (const float*)d_in[8];
    const float* b_lin     = (const float*)d_in[9];
    float* out = (float*)d_out;

    float* ws    = (float*)d_ws;
    float* ws_m  = ws;                                   // 64*50*128 f32
    float* ws_c  = ws + BATCH * NSENT * EMBED;           // 64*50*128 f32
    float* ws_u  = ws + 2 * BATCH * NSENT * EMBED;       // 64*128 f32
    __bf16* ws_ubf = (__bf16*)(ws + 2 * BATCH * NSENT * EMBED + BATCH * EMBED);

    k_embed<<<dim3(NWARM + NMC + BATCH), dim3(256), 0, stream>>>(
        stories, masks, questions, W_A, W_B, W_C, W_AT, W_CT, W_lin,
        ws_m, ws_c, ws_u);
    k_hops<<<dim3(BATCH), dim3(256), 0, stream>>>(ws_m, ws_c, ws_u, ws_ubf);
    k_out<<<dim3((VOCAB + VT - 1) / VT), dim3(256), 0, stream>>>(ws_ubf, W_lin, b_lin, out);
}